// Round 1
// baseline (333.464 us; speedup 1.0000x reference)
//
// PatchSampleF: gather + 2-layer MLP + L2-normalize, bf16 MFMA implementation.
// R0: correctness-first baseline with sane tiling.
//   K1: fused gather->GEMM1(relu) -> h (bf16, in d_ws, 16 MiB)
//   K2: GEMM2 + bias + row L2-normalize -> out (fp32)
// MFMA: v_mfma_f32_16x16x32_bf16, C/D layout col=lane&15, row=(lane>>4)*4+reg.
// LDS tiles XOR-swizzled (byte ^= (row&7)<<4) to kill the 128B-stride bank conflict.
#include <hip/hip_runtime.h>
#include <hip/hip_bf16.h>

typedef __bf16 bf16x8 __attribute__((ext_vector_type(8)));
typedef __bf16 bf16x4 __attribute__((ext_vector_type(4)));
typedef __bf16 bf16x2 __attribute__((ext_vector_type(2)));
typedef float  f32x4  __attribute__((ext_vector_type(4)));

constexpr int Bn  = 16;
constexpr int Cc  = 512;
constexpr int HWn = 4096;
constexpr int Pn  = 2048;
constexpr int NC  = 256;
constexpr int Mtot = Bn * Pn;   // 32768 rows
constexpr int BM   = 128;       // rows per block (never crosses an image: 2048%128==0)
constexpr int NTHR = 512;       // 8 waves: 4 (M) x 2 (N)

__device__ __forceinline__ int swz(int row, int byte_in_row) {
  // rows are 128 B (64 bf16); XOR bits 4..6 with row&7 -> 2-way max on b128 reads
  return row * 128 + (byte_in_row ^ ((row & 7) << 4));
}

// ---------------------------------------------------------------- kernel 1
__global__ __launch_bounds__(NTHR, 2)
void k_gemm1(const float* __restrict__ feat, const int* __restrict__ pid,
             const float* __restrict__ w1, const float* __restrict__ b1,
             __bf16* __restrict__ h) {
  __shared__ __align__(16) char sA[BM * 128];   // 128 rows x 64 bf16 (x tile)
  __shared__ __align__(16) char sB[NC * 128];   // 256 rows x 64 bf16 (w1 tile)
  __shared__ int sPid[BM];

  const int tid = threadIdx.x;
  const int m0  = blockIdx.x * BM;
  const int img = m0 >> 11;          // which b (2048 rows per image)
  const int p0  = m0 & (Pn - 1);

  if (tid < BM) sPid[tid] = pid[p0 + tid];
  __syncthreads();

  const int wid = tid >> 6, lane = tid & 63;
  const int wm = wid >> 1, wn = wid & 1;      // wave tile: 32 rows x 128 cols
  const int g = lane >> 4, ln = lane & 15;

  f32x4 acc[2][8];
  #pragma unroll
  for (int rt = 0; rt < 2; ++rt)
    #pragma unroll
    for (int ct = 0; ct < 8; ++ct) acc[rt][ct] = (f32x4){0.f, 0.f, 0.f, 0.f};

  for (int kt = 0; kt < Cc / 64; ++kt) {
    const int k0 = kt * 64;
    // stage A: gather 128 rows x 64 ch from feat (random-in-plane, L1/L2 served)
    #pragma unroll
    for (int r = 0; r < 8; ++r) {
      int idx = tid + r * NTHR;            // 0..4095 = 128 mm x 32 k-pairs
      int mm = idx & 127, k2 = idx >> 7;
      const float* fp = feat + (((size_t)(img * Cc + k0 + 2 * k2)) << 12) + sPid[mm];
      float f0 = fp[0], f1 = fp[HWn];      // two adjacent channel planes
      bf16x2 v; v[0] = (__bf16)f0; v[1] = (__bf16)f1;
      *(unsigned int*)(sA + swz(mm, k2 * 4)) = __builtin_bit_cast(unsigned int, v);
    }
    // stage B: w1 tile 256 n x 64 k, fp32 -> bf16
    #pragma unroll
    for (int r = 0; r < 8; ++r) {
      int idx = tid + r * NTHR;            // 0..4095 = 256 n x 16 float4
      int n = idx >> 4, kq = idx & 15;
      float4 f = *(const float4*)(w1 + (size_t)n * Cc + k0 + kq * 4);
      bf16x4 v; v[0] = (__bf16)f.x; v[1] = (__bf16)f.y; v[2] = (__bf16)f.z; v[3] = (__bf16)f.w;
      *(uint2*)(sB + swz(n, kq * 8)) = __builtin_bit_cast(uint2, v);
    }
    __syncthreads();
    #pragma unroll
    for (int ki = 0; ki < 2; ++ki) {
      bf16x8 a0 = *(const bf16x8*)(sA + swz(wm * 32 + ln,      ki * 64 + g * 16));
      bf16x8 a1 = *(const bf16x8*)(sA + swz(wm * 32 + 16 + ln, ki * 64 + g * 16));
      #pragma unroll
      for (int ct = 0; ct < 8; ++ct) {
        bf16x8 bv = *(const bf16x8*)(sB + swz(wn * 128 + ct * 16 + ln, ki * 64 + g * 16));
        acc[0][ct] = __builtin_amdgcn_mfma_f32_16x16x32_bf16(a0, bv, acc[0][ct], 0, 0, 0);
        acc[1][ct] = __builtin_amdgcn_mfma_f32_16x16x32_bf16(a1, bv, acc[1][ct], 0, 0, 0);
      }
    }
    __syncthreads();
  }

  // epilogue: bias + relu -> h (bf16)
  #pragma unroll
  for (int ct = 0; ct < 8; ++ct) {
    const int col = wn * 128 + ct * 16 + ln;
    const float bias = b1[col];
    #pragma unroll
    for (int rt = 0; rt < 2; ++rt)
      #pragma unroll
      for (int j = 0; j < 4; ++j) {
        int row = m0 + wm * 32 + rt * 16 + g * 4 + j;
        float v = acc[rt][ct][j] + bias;
        v = v > 0.f ? v : 0.f;
        h[(size_t)row * NC + col] = (__bf16)v;
      }
  }
}

// ---------------------------------------------------------------- kernel 2
__global__ __launch_bounds__(NTHR, 2)
void k_gemm2(const __bf16* __restrict__ h, const float* __restrict__ w2,
             const float* __restrict__ b2, float* __restrict__ out) {
  __shared__ __align__(16) char sA[BM * 128];
  __shared__ __align__(16) char sB[NC * 128];
  __shared__ float sRS[BM][2];

  const int tid = threadIdx.x;
  const int m0  = blockIdx.x * BM;
  const int wid = tid >> 6, lane = tid & 63;
  const int wm = wid >> 1, wn = wid & 1;
  const int g = lane >> 4, ln = lane & 15;

  f32x4 acc[2][8];
  #pragma unroll
  for (int rt = 0; rt < 2; ++rt)
    #pragma unroll
    for (int ct = 0; ct < 8; ++ct) acc[rt][ct] = (f32x4){0.f, 0.f, 0.f, 0.f};

  const char* hb = (const char*)h;
  for (int kt = 0; kt < NC / 64; ++kt) {
    const int k0 = kt * 64;
    // stage A: h tile (already bf16), 128 rows x 128 B
    #pragma unroll
    for (int r = 0; r < 2; ++r) {
      int idx = tid + r * NTHR;            // 0..1023 = 128 mm x 8 chunks
      int mm = idx >> 3, c8 = idx & 7;
      uint4 v = *(const uint4*)(hb + (size_t)(m0 + mm) * 512 + k0 * 2 + c8 * 16);
      *(uint4*)(sA + swz(mm, c8 * 16)) = v;
    }
    // stage B: w2 tile 256 n x 64 k, fp32 -> bf16
    #pragma unroll
    for (int r = 0; r < 8; ++r) {
      int idx = tid + r * NTHR;
      int n = idx >> 4, kq = idx & 15;
      float4 f = *(const float4*)(w2 + (size_t)n * NC + k0 + kq * 4);
      bf16x4 v; v[0] = (__bf16)f.x; v[1] = (__bf16)f.y; v[2] = (__bf16)f.z; v[3] = (__bf16)f.w;
      *(uint2*)(sB + swz(n, kq * 8)) = __builtin_bit_cast(uint2, v);
    }
    __syncthreads();
    #pragma unroll
    for (int ki = 0; ki < 2; ++ki) {
      bf16x8 a0 = *(const bf16x8*)(sA + swz(wm * 32 + ln,      ki * 64 + g * 16));
      bf16x8 a1 = *(const bf16x8*)(sA + swz(wm * 32 + 16 + ln, ki * 64 + g * 16));
      #pragma unroll
      for (int ct = 0; ct < 8; ++ct) {
        bf16x8 bv = *(const bf16x8*)(sB + swz(wn * 128 + ct * 16 + ln, ki * 64 + g * 16));
        acc[0][ct] = __builtin_amdgcn_mfma_f32_16x16x32_bf16(a0, bv, acc[0][ct], 0, 0, 0);
        acc[1][ct] = __builtin_amdgcn_mfma_f32_16x16x32_bf16(a1, bv, acc[1][ct], 0, 0, 0);
      }
    }
    __syncthreads();
  }

  // epilogue: bias, row sum-of-squares (16-lane shfl + cross-wave LDS), normalize
  float ss[2][4] = {{0.f,0.f,0.f,0.f},{0.f,0.f,0.f,0.f}};
  #pragma unroll
  for (int ct = 0; ct < 8; ++ct) {
    const int col = wn * 128 + ct * 16 + ln;
    const float bias = b2[col];
    #pragma unroll
    for (int rt = 0; rt < 2; ++rt)
      #pragma unroll
      for (int j = 0; j < 4; ++j) {
        float v = acc[rt][ct][j] + bias;
        acc[rt][ct][j] = v;
        ss[rt][j] += v * v;
      }
  }
  #pragma unroll
  for (int mk = 1; mk < 16; mk <<= 1)
    #pragma unroll
    for (int rt = 0; rt < 2; ++rt)
      #pragma unroll
      for (int j = 0; j < 4; ++j)
        ss[rt][j] += __shfl_xor(ss[rt][j], mk);
  if (ln == 0) {
    #pragma unroll
    for (int rt = 0; rt < 2; ++rt)
      #pragma unroll
      for (int j = 0; j < 4; ++j)
        sRS[wm * 32 + rt * 16 + g * 4 + j][wn] = ss[rt][j];
  }
  __syncthreads();
  float sc[2][4];
  #pragma unroll
  for (int rt = 0; rt < 2; ++rt)
    #pragma unroll
    for (int j = 0; j < 4; ++j) {
      int row = wm * 32 + rt * 16 + g * 4 + j;
      float t = sRS[row][0] + sRS[row][1];
      sc[rt][j] = 1.f / (sqrtf(t) + 1e-7f);
    }
  #pragma unroll
  for (int ct = 0; ct < 8; ++ct) {
    const int col = wn * 128 + ct * 16 + ln;
    #pragma unroll
    for (int rt = 0; rt < 2; ++rt)
      #pragma unroll
      for (int j = 0; j < 4; ++j) {
        int row = wm * 32 + rt * 16 + g * 4 + j;
        out[(size_t)(m0 + row) * NC + col] = acc[rt][ct][j] * sc[rt][j];
      }
  }
}

// ---------------------------------------------------------------- launch
extern "C" void kernel_launch(void* const* d_in, const int* in_sizes, int n_in,
                              void* d_out, int out_size, void* d_ws, size_t ws_size,
                              hipStream_t stream) {
  const float* feat = (const float*)d_in[0];
  const int*   pid  = (const int*)d_in[1];     // JAX int64 request falls back to int32
  const float* w1   = (const float*)d_in[2];
  const float* b1   = (const float*)d_in[3];
  const float* w2   = (const float*)d_in[4];
  const float* b2   = (const float*)d_in[5];
  float*  out  = (float*)d_out;
  __bf16* hbuf = (__bf16*)d_ws;                // 32768*256*2B = 16 MiB scratch

  k_gemm1<<<Mtot / BM, NTHR, 0, stream>>>(feat, pid, w1, b1, hbuf);
  k_gemm2<<<Mtot / BM, NTHR, 0, stream>>>(hbuf, w2, b2, out);
}

// Round 2
// 264.636 us; speedup vs baseline: 1.2601x; 1.2601x over previous
//
// PatchSampleF R2: dense GEMM1 (kills the 4B random gather) + gather GEMM2.
//   K1: h_dense[b*4096+hw, n] = relu(feat[b,:,hw] . w1[n,:] + b1[n]) for ALL hw.
//       feat read coalesced exactly once (128 MB); A direct-to-reg, B in LDS.
//   K2: gather rows of h_dense by patch_id (512B contiguous rows), GEMM2,
//       bias + row L2-normalize -> out (fp32).
// MFMA: v_mfma_f32_16x16x32_bf16; C/D layout col=lane&15, row=(lane>>4)*4+reg.
// LDS XOR-swizzle (byte ^= (row&7)<<4) on all 128B-row tiles.
#include <hip/hip_runtime.h>
#include <hip/hip_bf16.h>

typedef __bf16 bf16x8 __attribute__((ext_vector_type(8)));
typedef __bf16 bf16x4 __attribute__((ext_vector_type(4)));
typedef float  f32x4  __attribute__((ext_vector_type(4)));

constexpr int Bn  = 16;
constexpr int Cc  = 512;
constexpr int HWn = 4096;
constexpr int Pn  = 2048;
constexpr int NC  = 256;
constexpr int Mdense = Bn * HWn;  // 65536 dense rows
constexpr int Mout   = Bn * Pn;   // 32768 output rows
constexpr int BM   = 128;
constexpr int NTHR = 512;         // 8 waves: 4(M) x 2(N)

__device__ __forceinline__ int swz(int row, int byte_in_row) {
  return row * 128 + (byte_in_row ^ ((row & 7) << 4));
}

__device__ __forceinline__ f32x4 mfma16(bf16x8 a, bf16x8 b, f32x4 c) {
  return __builtin_amdgcn_mfma_f32_16x16x32_bf16(a, b, c, 0, 0, 0);
}

// ------------------------------------------------ K1: dense MLP layer 1
__global__ __launch_bounds__(NTHR, 4)
void k1_dense(const float* __restrict__ feat, const float* __restrict__ w1,
              const float* __restrict__ b1, __bf16* __restrict__ h) {
  __shared__ __align__(16) char sB[NC * 128];   // w1 tile: 256 n x 64 k bf16

  const int tid = threadIdx.x;
  const int m0  = blockIdx.x * BM;
  const int b   = m0 >> 12;            // image (4096 rows per image)
  const int hw0 = m0 & (HWn - 1);
  const int wid = tid >> 6, lane = tid & 63;
  const int wm = wid >> 1, wn = wid & 1;   // wave tile 32 rows x 128 cols
  const int g = lane >> 4, ln = lane & 15;

  f32x4 acc[2][8];
  #pragma unroll
  for (int rt = 0; rt < 2; ++rt)
    #pragma unroll
    for (int ct = 0; ct < 8; ++ct) acc[rt][ct] = (f32x4){0.f, 0.f, 0.f, 0.f};

  // per-lane A base: channel (g*8), position hw0 + wm*32 + ln  (contiguous in lane)
  const float* gA0 = feat + (((size_t)(b * Cc + g * 8)) << 12) + hw0 + wm * 32 + ln;
  const float* gA1 = gA0 + 16;

  for (int kt = 0; kt < Cc / 64; ++kt) {
    // A-frags direct to registers: 8 plane-strided scalar loads per (rt,ki).
    // Each wave-load = 4 channels x 16 contiguous positions = 4 fully-used 64B segs.
    bf16x8 af[2][2];
    const float* p0 = gA0 + (((size_t)(kt * 64)) << 12);
    const float* p1 = gA1 + (((size_t)(kt * 64)) << 12);
    #pragma unroll
    for (int ki = 0; ki < 2; ++ki)
      #pragma unroll
      for (int j = 0; j < 8; ++j) {
        af[0][ki][j] = (__bf16)p0[((size_t)(ki * 32 + j)) << 12];
        af[1][ki][j] = (__bf16)p1[((size_t)(ki * 32 + j)) << 12];
      }
    // B stage: w1 256 n x 64 k, fp32 -> bf16, swizzled LDS
    #pragma unroll
    for (int r = 0; r < 8; ++r) {
      int idx = tid + r * NTHR;          // 4096 = 256 n x 16 float4
      int n = idx >> 4, kq = idx & 15;
      float4 f = *(const float4*)(w1 + (size_t)n * Cc + kt * 64 + kq * 4);
      bf16x4 v; v[0] = (__bf16)f.x; v[1] = (__bf16)f.y; v[2] = (__bf16)f.z; v[3] = (__bf16)f.w;
      *(uint2*)(sB + swz(n, kq * 8)) = __builtin_bit_cast(uint2, v);
    }
    __syncthreads();
    #pragma unroll
    for (int ki = 0; ki < 2; ++ki)
      #pragma unroll
      for (int ct = 0; ct < 8; ++ct) {
        bf16x8 bv = *(const bf16x8*)(sB + swz(wn * 128 + ct * 16 + ln, ki * 64 + g * 16));
        acc[0][ct] = mfma16(af[0][ki], bv, acc[0][ct]);
        acc[1][ct] = mfma16(af[1][ki], bv, acc[1][ct]);
      }
    __syncthreads();
  }

  // epilogue: bias + relu -> h_dense (bf16)
  #pragma unroll
  for (int ct = 0; ct < 8; ++ct) {
    const int col = wn * 128 + ct * 16 + ln;
    const float bias = b1[col];
    #pragma unroll
    for (int rt = 0; rt < 2; ++rt)
      #pragma unroll
      for (int j = 0; j < 4; ++j) {
        int row = m0 + wm * 32 + rt * 16 + g * 4 + j;
        float v = acc[rt][ct][j] + bias;
        h[(size_t)row * NC + col] = (__bf16)(v > 0.f ? v : 0.f);
      }
  }
}

// ------------------------------------------------ K2: gather + layer 2 + L2norm
__global__ __launch_bounds__(NTHR, 2)
void k2_gather(const __bf16* __restrict__ h, const int* __restrict__ pid,
               const float* __restrict__ w2, const float* __restrict__ b2,
               float* __restrict__ out) {
  __shared__ __align__(16) char sA[BM * 128];
  __shared__ __align__(16) char sB[NC * 128];
  __shared__ int sRow[BM];
  __shared__ float sRS[BM][2];

  const int tid = threadIdx.x;
  const int m0  = blockIdx.x * BM;
  const int img = m0 >> 11;            // 2048 rows per image
  const int p0  = m0 & (Pn - 1);
  if (tid < BM) sRow[tid] = img * HWn + pid[p0 + tid];
  __syncthreads();

  const int wid = tid >> 6, lane = tid & 63;
  const int wm = wid >> 1, wn = wid & 1;
  const int g = lane >> 4, ln = lane & 15;

  f32x4 acc[2][8];
  #pragma unroll
  for (int rt = 0; rt < 2; ++rt)
    #pragma unroll
    for (int ct = 0; ct < 8; ++ct) acc[rt][ct] = (f32x4){0.f, 0.f, 0.f, 0.f};

  const char* hb = (const char*)h;
  for (int kt = 0; kt < NC / 64; ++kt) {
    // stage A: gather 128 h_dense rows, 128B slice each (rows are 512B contiguous)
    #pragma unroll
    for (int r = 0; r < 2; ++r) {
      int idx = tid + r * NTHR;          // 1024 = 128 rows x 8 x 16B
      int mm = idx >> 3, c8 = idx & 7;
      uint4 v = *(const uint4*)(hb + (size_t)sRow[mm] * 512 + kt * 128 + c8 * 16);
      *(uint4*)(sA + swz(mm, c8 * 16)) = v;
    }
    // stage B: w2 tile 256 n x 64 k, fp32 -> bf16
    #pragma unroll
    for (int r = 0; r < 8; ++r) {
      int idx = tid + r * NTHR;
      int n = idx >> 4, kq = idx & 15;
      float4 f = *(const float4*)(w2 + (size_t)n * NC + kt * 64 + kq * 4);
      bf16x4 v; v[0] = (__bf16)f.x; v[1] = (__bf16)f.y; v[2] = (__bf16)f.z; v[3] = (__bf16)f.w;
      *(uint2*)(sB + swz(n, kq * 8)) = __builtin_bit_cast(uint2, v);
    }
    __syncthreads();
    #pragma unroll
    for (int ki = 0; ki < 2; ++ki) {
      bf16x8 a0 = *(const bf16x8*)(sA + swz(wm * 32 + ln,      ki * 64 + g * 16));
      bf16x8 a1 = *(const bf16x8*)(sA + swz(wm * 32 + 16 + ln, ki * 64 + g * 16));
      #pragma unroll
      for (int ct = 0; ct < 8; ++ct) {
        bf16x8 bv = *(const bf16x8*)(sB + swz(wn * 128 + ct * 16 + ln, ki * 64 + g * 16));
        acc[0][ct] = mfma16(a0, bv, acc[0][ct]);
        acc[1][ct] = mfma16(a1, bv, acc[1][ct]);
      }
    }
    __syncthreads();
  }

  // epilogue: bias, row sum-of-squares (16-lane shfl + cross-wave LDS), normalize
  float ss[2][4] = {{0.f,0.f,0.f,0.f},{0.f,0.f,0.f,0.f}};
  #pragma unroll
  for (int ct = 0; ct < 8; ++ct) {
    const int col = wn * 128 + ct * 16 + ln;
    const float bias = b2[col];
    #pragma unroll
    for (int rt = 0; rt < 2; ++rt)
      #pragma unroll
      for (int j = 0; j < 4; ++j) {
        float v = acc[rt][ct][j] + bias;
        acc[rt][ct][j] = v;
        ss[rt][j] += v * v;
      }
  }
  #pragma unroll
  for (int mk = 1; mk < 16; mk <<= 1)
    #pragma unroll
    for (int rt = 0; rt < 2; ++rt)
      #pragma unroll
      for (int j = 0; j < 4; ++j)
        ss[rt][j] += __shfl_xor(ss[rt][j], mk);
  if (ln == 0) {
    #pragma unroll
    for (int rt = 0; rt < 2; ++rt)
      #pragma unroll
      for (int j = 0; j < 4; ++j)
        sRS[wm * 32 + rt * 16 + g * 4 + j][wn] = ss[rt][j];
  }
  __syncthreads();
  float sc[2][4];
  #pragma unroll
  for (int rt = 0; rt < 2; ++rt)
    #pragma unroll
    for (int j = 0; j < 4; ++j) {
      int row = wm * 32 + rt * 16 + g * 4 + j;
      float t = sRS[row][0] + sRS[row][1];
      sc[rt][j] = 1.f / (sqrtf(t) + 1e-7f);
    }
  #pragma unroll
  for (int ct = 0; ct < 8; ++ct) {
    const int col = wn * 128 + ct * 16 + ln;
    #pragma unroll
    for (int rt = 0; rt < 2; ++rt)
      #pragma unroll
      for (int j = 0; j < 4; ++j) {
        int row = wm * 32 + rt * 16 + g * 4 + j;
        out[(size_t)(m0 + row) * NC + col] = acc[rt][ct][j] * sc[rt][j];
      }
  }
}

// ------------------------------------------------ launch
extern "C" void kernel_launch(void* const* d_in, const int* in_sizes, int n_in,
                              void* d_out, int out_size, void* d_ws, size_t ws_size,
                              hipStream_t stream) {
  const float* feat = (const float*)d_in[0];
  const int*   pid  = (const int*)d_in[1];
  const float* w1   = (const float*)d_in[2];
  const float* b1   = (const float*)d_in[3];
  const float* w2   = (const float*)d_in[4];
  const float* b2   = (const float*)d_in[5];
  float*  out  = (float*)d_out;
  __bf16* hbuf = (__bf16*)d_ws;        // dense h: 65536*256*2B = 32 MiB scratch

  k1_dense <<<Mdense / BM, NTHR, 0, stream>>>(feat, w1, b1, hbuf);
  k2_gather<<<Mout   / BM, NTHR, 0, stream>>>(hbuf, pid, w2, b2, out);
}